// Round 20
// baseline (656.878 us; speedup 1.0000x reference)
//
#include <hip/hip_runtime.h>
#include <hip/hip_bf16.h>
#include <math.h>

#define HW 4096
#define WD 64
#define CDIM 256
#define BATCH 8
#define CHT 32
#define MROWS 2304   // per-batch rows: u(256) + slotA taps+lam(1024) + slotB(1024)

typedef __attribute__((ext_vector_type(8))) short s16x8;
typedef __attribute__((ext_vector_type(8))) __bf16 b16x8;
typedef __attribute__((ext_vector_type(4))) float f32x4;
typedef __attribute__((ext_vector_type(8))) unsigned short us16x8;

enum { E_NONE = 0, E_GELU = 2, E_RESPM = 4 };

__device__ __forceinline__ unsigned short f2bf(float f) {
    union { float f; unsigned u; } v; v.f = f;
    unsigned r = (v.u + 0x7fffu + ((v.u >> 16) & 1u)) >> 16;
    return (unsigned short)r;
}
__device__ __forceinline__ float bf2f(unsigned short h) {
    union { unsigned u; float f; } v; v.u = ((unsigned)h) << 16; return v.f;
}
// D.lo16 = bf16(lo), D.hi16 = bf16(hi); RNE. No builtin on gfx950 -> asm.
__device__ __forceinline__ unsigned cvt_pk_bf16(float lo, float hi) {
    unsigned r;
    asm("v_cvt_pk_bf16_f32 %0, %1, %2" : "=v"(r) : "v"(lo), "v"(hi));
    return r;
}

__device__ __forceinline__ void gload16(const void* g, void* l) {
    __builtin_amdgcn_global_load_lds(
        (const __attribute__((address_space(1))) void*)g,
        (__attribute__((address_space(3))) void*)l, 16, 0, 0);
}

__device__ __forceinline__ f32x4 mfma_bf16(s16x8 a, s16x8 b, f32x4 c) {
    return __builtin_amdgcn_mfma_f32_16x16x32_bf16(
        __builtin_bit_cast(b16x8, a), __builtin_bit_cast(b16x8, b), c, 0, 0, 0);
}

// Pack all weights to bf16 [M][K] row-major blocks + packed bias vector.
__global__ __launch_bounds__(256) void pack_weights(
    const float* __restrict__ Wu, const float* __restrict__ Ww,
    const float* __restrict__ Wl, const float* __restrict__ Wo,
    const float* __restrict__ W1, const float* __restrict__ W2,
    const float* __restrict__ bu, const float* __restrict__ bw,
    const float* __restrict__ bl, const float* __restrict__ bo,
    const float* __restrict__ b1, const float* __restrict__ b2,
    unsigned short* __restrict__ Wt, float* __restrict__ biasP)
{
    const int gid = blockIdx.x * 256 + threadIdx.x;
    if (gid < 1703936) {
        float v;
        if (gid < 65536) { v = Wu[gid]; }
        else if (gid < 1114112) {
            int t = gid - 65536; int d = t >> 18; int r = t & 262143;
            int m = r >> 8; int k = r & 255;
            v = (m < 768) ? Ww[(size_t)(d * 768 + m) * 256 + k]
                          : Wl[(size_t)(d * 256 + (m - 768)) * 256 + k];
        }
        else if (gid < 1179648) { v = Wo[gid - 1114112]; }
        else if (gid < 1441792) {
            int t = gid - 1179648; int m = t >> 8; int k = t & 255;
            v = W1[(size_t)k * 1024 + m];
        }
        else {
            int t = gid - 1441792; int m = t >> 10; int k = t & 1023;
            v = W2[(size_t)k * 256 + m];
        }
        Wt[gid] = f2bf(v);
    }
    if (gid < 5888) {
        float v;
        if (gid < 256) v = bu[gid];
        else if (gid < 4352) {
            int t = gid - 256; int d = t >> 10; int r = t & 1023;
            v = (r < 768) ? bw[d * 768 + r] : bl[d * 256 + (r - 768)];
        }
        else if (gid < 4608) v = bo[gid - 4352];
        else if (gid < 5632) v = b1[gid - 4608];
        else v = b2[gid - 5632];
        biasP[gid] = v;
    }
}

// fp32 channel-major [B][256][4096] -> bf16 pixel-major [B][4096][256]
__global__ __launch_bounds__(256) void transpose_to_bf(
    const float* __restrict__ src, unsigned short* __restrict__ dst)
{
    __shared__ float T[64][65];
    const int t = threadIdx.x;
    const int n0 = blockIdx.x * 64, c0 = blockIdx.y * 64, b = blockIdx.z;
    const int nl = t & 63, cg = t >> 6;
#pragma unroll
    for (int i = 0; i < 16; ++i) {
        int cl = cg + i * 4;
        T[cl][nl] = src[((size_t)b * 256 + c0 + cl) * HW + n0 + nl];
    }
    __syncthreads();
#pragma unroll
    for (int i = 0; i < 16; ++i) {
        int nl2 = cg + i * 4;
        dst[((size_t)b * HW + n0 + nl2) * 256 + c0 + (t & 63)] = f2bf(T[t & 63][nl2]);
    }
}

// MFMA GEMM, 128x128 tile, 4 waves 2x2, 16x16x32, BK=32 (r15-validated
// 2-buf counted pipeline). Mst = CM batch row-stride.
__global__ __launch_bounds__(256) void gemm_mfma(
    const unsigned short* __restrict__ Abf,
    const unsigned short* __restrict__ Wbf,
    const float* __restrict__ bias,
    int K, int M, int Mst,
    float* __restrict__ outCM,
    unsigned short* __restrict__ outCMh,
    unsigned short* __restrict__ outPM,
    const unsigned short* __restrict__ resPM,
    int epi)
{
    __shared__ __align__(16) char SMEM[32768];     // 2 bufs x (A 8KB + B 8KB)
    const int tid = threadIdx.x;
    const int w = tid >> 6, l = tid & 63;
    const int n0 = blockIdx.x * 128;
    const int m0 = blockIdx.y * 128;
    const int bz = blockIdx.z;
    const int wpi = w >> 1, wcj = w & 1;
    const int lr = l & 15, lg = l >> 4;

    const unsigned short* Ab = Abf + (size_t)bz * HW * K;

    f32x4 acc[4][4];
#pragma unroll
    for (int i = 0; i < 4; ++i)
#pragma unroll
        for (int j = 0; j < 4; ++j) acc[i][j] = (f32x4)0.f;

    const int sko = (((l & 3) ^ ((l >> 3) & 3)) * 8);   // swizzled k-chunk (elems)
    const int rsw = (lr >> 1) & 3;                      // read-side XOR
    const int row_l = (l >> 2);

    const int c0 = w * 2, c1 = c0 + 1;
    const unsigned short* pA0 = Ab  + (size_t)(n0 + c0 * 16 + row_l) * K + sko;
    const unsigned short* pA1 = Ab  + (size_t)(n0 + c1 * 16 + row_l) * K + sko;
    const unsigned short* pB0 = Wbf + (size_t)(m0 + c0 * 16 + row_l) * K + sko;
    const unsigned short* pB1 = Wbf + (size_t)(m0 + c1 * 16 + row_l) * K + sko;
    const int dA0 = c0 * 1024, dA1 = c1 * 1024;
    const int dB0 = 8192 + c0 * 1024, dB1 = 8192 + c1 * 1024;

#define STAGE(buf, kk)                                                         \
    {                                                                          \
        gload16(pA0 + (kk), SMEM + (buf) * 16384 + dA0);                       \
        gload16(pB0 + (kk), SMEM + (buf) * 16384 + dB0);                       \
        gload16(pA1 + (kk), SMEM + (buf) * 16384 + dA1);                       \
        gload16(pB1 + (kk), SMEM + (buf) * 16384 + dB1);                       \
    }

    const int NS = K >> 5;
    STAGE(0, 0);
    int cur = 0;
    for (int t = 0; t < NS; ++t) {
        if (t + 1 < NS) {
            STAGE(cur ^ 1, (t + 1) * 32);
            asm volatile("s_waitcnt vmcnt(4)" ::: "memory");
        } else {
            asm volatile("s_waitcnt vmcnt(0)" ::: "memory");
        }
        __builtin_amdgcn_s_barrier();
        const short* Ac = (const short*)(SMEM + cur * 16384);
        const short* Bc = (const short*)(SMEM + cur * 16384 + 8192);
        s16x8 av[4], bv[4];
#pragma unroll
        for (int f = 0; f < 4; ++f) {
            av[f] = *(const s16x8*)&Ac[(wpi * 64 + f * 16 + lr) * 32 + (lg ^ rsw) * 8];
            bv[f] = *(const s16x8*)&Bc[(wcj * 64 + f * 16 + lr) * 32 + (lg ^ rsw) * 8];
        }
        __builtin_amdgcn_s_setprio(1);
#pragma unroll
        for (int fi = 0; fi < 4; ++fi)
#pragma unroll
            for (int fj = 0; fj < 4; ++fj)
                acc[fi][fj] = mfma_bf16(av[fi], bv[fj], acc[fi][fj]);
        __builtin_amdgcn_s_setprio(0);
        __builtin_amdgcn_s_barrier();
        cur ^= 1;
    }
#undef STAGE

    unsigned short* RP = (unsigned short*)SMEM;    // 128x128 bf16 PM repack

#pragma unroll
    for (int fi = 0; fi < 4; ++fi) {
#pragma unroll
        for (int fj = 0; fj < 4; ++fj) {
            const int m = m0 + wcj * 64 + fj * 16 + lr;
            const int nl = wpi * 64 + fi * 16 + lg * 4;
            const float bs = bias[m];
            const size_t oc = ((size_t)bz * Mst + m) * HW + n0 + nl;
            float4 v4;
            float* vp = &v4.x;
#pragma unroll
            for (int r = 0; r < 4; ++r) vp[r] = acc[fi][fj][r] + bs;
            if (epi == E_GELU) {
                // x*sigmoid(1.702x): |err| <= 0.021 vs exact-erf GELU
#pragma unroll
                for (int r = 0; r < 4; ++r)
                    vp[r] = vp[r] / (1.f + __expf(-1.702f * vp[r]));
            } else if (epi == E_RESPM) {
#pragma unroll
                for (int r = 0; r < 4; ++r)
                    vp[r] += bf2f(resPM[((size_t)bz * HW + n0 + nl + r) * 256 + m]);
            }
            if (outCM)  *(float4*)&outCM[oc] = v4;
            if (outCMh) {
                uint2 p;
                p.x = cvt_pk_bf16(v4.x, v4.y);
                p.y = cvt_pk_bf16(v4.z, v4.w);
                *(uint2*)&outCMh[oc] = p;
            }
            if (outPM) {
                const int ml = wcj * 64 + fj * 16 + lr;
                const unsigned p01 = cvt_pk_bf16(vp[0], vp[1]);
                const unsigned p23 = cvt_pk_bf16(vp[2], vp[3]);
                RP[(nl + 0) * 128 + ml] = (unsigned short)p01;
                RP[(nl + 1) * 128 + ml] = (unsigned short)(p01 >> 16);
                RP[(nl + 2) * 128 + ml] = (unsigned short)p23;
                RP[(nl + 3) * 128 + ml] = (unsigned short)(p23 >> 16);
            }
        }
    }

    if (outPM) {
        __syncthreads();
#pragma unroll
        for (int i = 0; i < 8; ++i) {
            const int flat = i * 4096 + tid * 16;
            const int nl = flat >> 8;
            const int mlb = flat & 255;
            *(us16x8*)&outPM[((size_t)bz * HW + n0 + nl) * M + m0 + (mlb >> 1)] =
                *(const us16x8*)((const char*)RP + flat);
        }
    }
}

// Fused bidirectional ROW scans (dir0 top-down + dir1 bottom-up) in one
// pass. Two independent chains per wave (forced ILP-2 under the serial
// shfl dependency); y accumulated in a fully-unrolled register array
// (compile-time indices) and written ONCE (no RMW pass).
__global__ __launch_bounds__(256) void scan_rows2(
    const unsigned short* __restrict__ uwl, float* __restrict__ y)
{
    const int wave = threadIdx.x >> 6;
    const int lane = threadIdx.x & 63;
    const int plane = blockIdx.x * 4 + wave;
    const int b = plane >> 8;
    const int c = plane & 255;

    const size_t base  = (size_t)b * ((size_t)MROWS * HW) + (size_t)c * HW;
    const size_t tap   = (size_t)CDIM * HW;
    const unsigned short* u  = uwl + base;                       // rows 0-255
    const unsigned short* wA = uwl + base + (size_t)256 * HW;    // dir0 taps
    const unsigned short* lA = uwl + base + (size_t)1024 * HW;   // dir0 lam
    const unsigned short* wB = uwl + base + (size_t)1280 * HW;   // dir1 taps
    const unsigned short* lB = uwl + base + (size_t)2048 * HW;   // dir1 lam
    const size_t base_y = ((size_t)b * CDIM + c) * HW;

    float yacc[64];
#pragma unroll
    for (int r = 0; r < 64; ++r) yacc[r] = 0.f;

    float h0 = 0.f, h1 = 0.f;
#pragma unroll
    for (int s = 0; s < 64; ++s) {
        const int r0 = s, r1 = 63 - s;
        const size_t o0 = (size_t)r0 * WD + lane;
        const size_t o1 = (size_t)r1 * WD + lane;
        // chain0: dir0, slot A
        float a0 = bf2f(wA[o0]), a1 = bf2f(wA[tap + o0]), a2 = bf2f(wA[2 * tap + o0]);
        float al = 1.f / (1.f + __expf(-bf2f(lA[o0])));
        float au = bf2f(u[o0]);
        float dnA = 1.f / (fabsf(a0) + fabsf(a1) + fabsf(a2) + 1e-6f);
        // chain1: dir1, slot B
        float b0 = bf2f(wB[o1]), b1v = bf2f(wB[tap + o1]), b2 = bf2f(wB[2 * tap + o1]);
        float bl = 1.f / (1.f + __expf(-bf2f(lB[o1])));
        float bu = bf2f(u[o1]);
        float dnB = 1.f / (fabsf(b0) + fabsf(b1v) + fabsf(b2) + 1e-6f);

        float h0l = __shfl_up(h0, 1), h0r = __shfl_down(h0, 1);
        float h1l = __shfl_up(h1, 1), h1r = __shfl_down(h1, 1);
        if (lane == 0)  { h0l = 0.f; h1l = 0.f; }
        if (lane == 63) { h0r = 0.f; h1r = 0.f; }

        h0 = (a0 * h0l + a1 * h0 + a2 * h0r) * dnA + al * au;
        h1 = (b0 * h1l + b1v * h1 + b2 * h1r) * dnB + bl * bu;
        yacc[r0] += h0;
        yacc[r1] += h1;
    }
#pragma unroll
    for (int r = 0; r < 64; ++r)
        y[base_y + (size_t)r * WD + lane] = yacc[r];
}

// Fused bidirectional COLUMN scans (dir2 left-right + dir3 right-left).
// One wave per plane; both slots' taps staged in LDS (49.3 KB -> 3 blocks/CU);
// h written into the U tiles, committed via the r15-validated coalesced YRMW.
// y RMW happens ONCE per element (chunks of the two chains are disjoint).
__global__ __launch_bounds__(64) void scan_cols2(
    const unsigned short* __restrict__ uwl, float* __restrict__ y)
{
    __shared__ unsigned short THa[4][CHT][66], THb[4][CHT][66];  // 2 x 16.5 KB
    __shared__ float Ua[CHT][65], Ub[CHT][65];                   // 2 x 8.1 KB
    const int lane = threadIdx.x;
    const int plane = blockIdx.x;
    const int b = plane >> 8;
    const int c = plane & 255;

    const size_t base  = (size_t)b * ((size_t)MROWS * HW) + (size_t)c * HW;
    const size_t tap   = (size_t)CDIM * HW;
    const unsigned short* u  = uwl + base;
    const unsigned short* wA = uwl + base + (size_t)256 * HW;    // dir2 taps
    const unsigned short* lA = uwl + base + (size_t)1024 * HW;   // dir2 lam
    const unsigned short* wB = uwl + base + (size_t)1280 * HW;   // dir3 taps
    const unsigned short* lB = uwl + base + (size_t)2048 * HW;   // dir3 lam
    const size_t base_y = ((size_t)b * CDIM + c) * HW;

    const int rr4 = lane >> 2, q4 = lane & 3;
    const int rr8 = lane >> 3, q8 = lane & 7;

    auto STAGE_SLOT = [&](unsigned short (*TH)[CHT][66], float (*U)[65],
                          const unsigned short* w3, const unsigned short* lm, int p0) {
#pragma unroll
        for (int a = 0; a < 4; ++a) {
            const unsigned short* s = (a < 3) ? (w3 + a * tap) : lm;
#pragma unroll
            for (int i = 0; i < 4; ++i) {
                const int r = i * 16 + rr4;
                const us16x8 v = *(const us16x8*)(s + (size_t)r * WD + p0 + q4 * 8);
#pragma unroll
                for (int j = 0; j < 8; ++j) TH[a][q4 * 8 + j][r] = v[j];
            }
        }
#pragma unroll
        for (int i = 0; i < 4; ++i) {
            const int r = i * 16 + rr4;
            const us16x8 v = *(const us16x8*)(u + (size_t)r * WD + p0 + q4 * 8);
#pragma unroll
            for (int j = 0; j < 8; ++j) U[q4 * 8 + j][r] = bf2f(v[j]);
        }
    };
    auto YRMW = [&](float (*U)[65], int p0) {
#pragma unroll
        for (int i = 0; i < 8; ++i) {
            const int r = i * 8 + rr8;
            const size_t g = base_y + (size_t)r * WD + p0 + q8 * 4;
            float4 old = *(const float4*)(y + g);
            old.x += U[q8 * 4 + 0][r];
            old.y += U[q8 * 4 + 1][r];
            old.z += U[q8 * 4 + 2][r];
            old.w += U[q8 * 4 + 3][r];
            *(float4*)(y + g) = old;
        }
    };

    float h2 = 0.f, h3 = 0.f;
    for (int ph = 0; ph < 2; ++ph) {
        const int c2 = ph * CHT;          // chain2 cols: 0..31 then 32..63
        const int c3 = (1 - ph) * CHT;    // chain3 cols: 63..32 then 31..0

        STAGE_SLOT(THa, Ua, wA, lA, c2);
        STAGE_SLOT(THb, Ub, wB, lB, c3);
        // 1 wave: same-wave LDS ops are in-order; no barrier needed.

#pragma unroll
        for (int t = 0; t < CHT; ++t) {
            {   // chain2 (dir2, ascending)
                const int pp = t;
                float w0 = bf2f(THa[0][pp][lane]);
                float w1 = bf2f(THa[1][pp][lane]);
                float w2 = bf2f(THa[2][pp][lane]);
                float dn = 1.f / (fabsf(w0) + fabsf(w1) + fabsf(w2) + 1e-6f);
                float lm = 1.f / (1.f + __expf(-bf2f(THa[3][pp][lane])));
                float uu = Ua[pp][lane];
                float hl = __shfl_up(h2, 1), hr = __shfl_down(h2, 1);
                if (lane == 0)  hl = 0.f;
                if (lane == 63) hr = 0.f;
                h2 = (w0 * hl + w1 * h2 + w2 * hr) * dn + lm * uu;
                Ua[pp][lane] = h2;
            }
            {   // chain3 (dir3, descending)
                const int pp = CHT - 1 - t;
                float w0 = bf2f(THb[0][pp][lane]);
                float w1 = bf2f(THb[1][pp][lane]);
                float w2 = bf2f(THb[2][pp][lane]);
                float dn = 1.f / (fabsf(w0) + fabsf(w1) + fabsf(w2) + 1e-6f);
                float lm = 1.f / (1.f + __expf(-bf2f(THb[3][pp][lane])));
                float uu = Ub[pp][lane];
                float hl = __shfl_up(h3, 1), hr = __shfl_down(h3, 1);
                if (lane == 0)  hl = 0.f;
                if (lane == 63) hr = 0.f;
                h3 = (w0 * hl + w1 * h3 + w2 * hr) * dn + lm * uu;
                Ub[pp][lane] = h3;
            }
        }

        YRMW(Ua, c2);
        YRMW(Ub, c3);
    }
}

extern "C" void kernel_launch(void* const* d_in, const int* in_sizes, int n_in,
                              void* d_out, int out_size, void* d_ws, size_t ws_size,
                              hipStream_t stream)
{
    const float* x  = (const float*)d_in[0];
    const float* Wu = (const float*)d_in[1];
    const float* bu = (const float*)d_in[2];
    const float* Ww = (const float*)d_in[3];
    const float* bw = (const float*)d_in[4];
    const float* Wl = (const float*)d_in[5];
    const float* bl = (const float*)d_in[6];
    const float* Wo = (const float*)d_in[7];
    const float* bo = (const float*)d_in[8];
    const float* W1 = (const float*)d_in[9];
    const float* b1 = (const float*)d_in[10];
    const float* W2 = (const float*)d_in[11];
    const float* b2 = (const float*)d_in[12];
    float* out = (float*)d_out;

    // ws layout (~238 MB; 255 MB proven in round 1):
    // uwl: [8][2304][4096] bf16 -- rows 0-255 u, 256-1279 slotA, 1280-2303 slotB
    unsigned short* uwl = (unsigned short*)d_ws;
    float* y_  = (float*)(uwl + (size_t)BATCH * MROWS * HW);   // [8][256][4096] f32
    unsigned short* xT  = (unsigned short*)(y_ + 8388608);     // [8][4096][256] bf16
    unsigned short* yT  = xT + 8388608;
    unsigned short* x2T = yT + 8388608;
    unsigned short* Wt  = x2T + 8388608;
    float* biasP = (float*)(Wt + 1703936);
    unsigned short* hT = uwl;                                  // [8][4096][1024] bf16 alias

    dim3 blk(256);

    pack_weights<<<dim3(6656), blk, 0, stream>>>(Wu, Ww, Wl, Wo, W1, W2,
                                                 bu, bw, bl, bo, b1, b2, Wt, biasP);
    transpose_to_bf<<<dim3(64, 4, 8), blk, 0, stream>>>(x, xT);

    // G01: fused u(256) + dir0(1024) + dir1(1024), M=2304 contiguous in Wt
    gemm_mfma<<<dim3(32, 18, 8), blk, 0, stream>>>(
        xT, Wt, biasP, 256, 2304, MROWS, nullptr, uwl, nullptr, nullptr, E_NONE);
    // fused row scans (dir0 + dir1), y overwritten once
    scan_rows2<<<dim3(512), blk, 0, stream>>>(uwl, y_);

    // G23: dir2(1024) + dir3(1024) -> slots A/B (rows 256..2303)
    gemm_mfma<<<dim3(32, 16, 8), blk, 0, stream>>>(
        xT, Wt + 589824, biasP + 2304, 256, 2048, MROWS,
        nullptr, uwl + (size_t)256 * HW, nullptr, nullptr, E_NONE);
    // fused column scans (dir2 + dir3), one y RMW pass
    scan_cols2<<<dim3(2048), dim3(64), 0, stream>>>(uwl, y_);

    transpose_to_bf<<<dim3(64, 4, 8), blk, 0, stream>>>(y_, yT);

    // x2 = x + Wo @ y + bo : bf16 PM only; residual from xT (bf16 PM)
    gemm_mfma<<<dim3(32, 2, 8), blk, 0, stream>>>(yT, Wt + 1114112, biasP + 4352,
        256, 256, 256, nullptr, nullptr, x2T, xT, E_RESPM);
    // h = gelu(x2 @ W1 + b1) : bf16 PM only
    gemm_mfma<<<dim3(32, 8, 8), blk, 0, stream>>>(x2T, Wt + 1179648, biasP + 4608,
        256, 1024, 1024, nullptr, nullptr, hT, nullptr, E_GELU);
    // out = x2 + h @ W2 + b2 : f32 CM = d_out, residual from x2T (PM bf16)
    gemm_mfma<<<dim3(32, 2, 8), blk, 0, stream>>>(hT, Wt + 1441792, biasP + 5632,
        1024, 256, 256, out, nullptr, nullptr, x2T, E_RESPM);
}

// Round 21
// 413.464 us; speedup vs baseline: 1.5887x; 1.5887x over previous
//
#include <hip/hip_runtime.h>
#include <hip/hip_bf16.h>
#include <math.h>

#define HW 4096
#define WD 64
#define CDIM 256
#define BATCH 8
#define CHT 32
#define MROWS 1280   // per-batch rows in combined u+taps+lam buffer

typedef __attribute__((ext_vector_type(8))) short s16x8;
typedef __attribute__((ext_vector_type(8))) __bf16 b16x8;
typedef __attribute__((ext_vector_type(4))) float f32x4;
typedef __attribute__((ext_vector_type(8))) unsigned short us16x8;

enum { E_NONE = 0, E_GELU = 2, E_RESPM = 4 };

__device__ __forceinline__ unsigned short f2bf(float f) {
    union { float f; unsigned u; } v; v.f = f;
    unsigned r = (v.u + 0x7fffu + ((v.u >> 16) & 1u)) >> 16;
    return (unsigned short)r;
}
__device__ __forceinline__ float bf2f(unsigned short h) {
    union { unsigned u; float f; } v; v.u = ((unsigned)h) << 16; return v.f;
}
// D.lo16 = bf16(lo), D.hi16 = bf16(hi); RNE. No builtin on gfx950 -> asm.
__device__ __forceinline__ unsigned cvt_pk_bf16(float lo, float hi) {
    unsigned r;
    asm("v_cvt_pk_bf16_f32 %0, %1, %2" : "=v"(r) : "v"(lo), "v"(hi));
    return r;
}

__device__ __forceinline__ void gload16(const void* g, void* l) {
    __builtin_amdgcn_global_load_lds(
        (const __attribute__((address_space(1))) void*)g,
        (__attribute__((address_space(3))) void*)l, 16, 0, 0);
}

__device__ __forceinline__ f32x4 mfma_bf16(s16x8 a, s16x8 b, f32x4 c) {
    return __builtin_amdgcn_mfma_f32_16x16x32_bf16(
        __builtin_bit_cast(b16x8, a), __builtin_bit_cast(b16x8, b), c, 0, 0, 0);
}

// Pack all weights to bf16 [M][K] row-major blocks + packed bias vector.
__global__ __launch_bounds__(256) void pack_weights(
    const float* __restrict__ Wu, const float* __restrict__ Ww,
    const float* __restrict__ Wl, const float* __restrict__ Wo,
    const float* __restrict__ W1, const float* __restrict__ W2,
    const float* __restrict__ bu, const float* __restrict__ bw,
    const float* __restrict__ bl, const float* __restrict__ bo,
    const float* __restrict__ b1, const float* __restrict__ b2,
    unsigned short* __restrict__ Wt, float* __restrict__ biasP)
{
    const int gid = blockIdx.x * 256 + threadIdx.x;
    if (gid < 1703936) {
        float v;
        if (gid < 65536) { v = Wu[gid]; }
        else if (gid < 1114112) {
            int t = gid - 65536; int d = t >> 18; int r = t & 262143;
            int m = r >> 8; int k = r & 255;
            v = (m < 768) ? Ww[(size_t)(d * 768 + m) * 256 + k]
                          : Wl[(size_t)(d * 256 + (m - 768)) * 256 + k];
        }
        else if (gid < 1179648) { v = Wo[gid - 1114112]; }
        else if (gid < 1441792) {
            int t = gid - 1179648; int m = t >> 8; int k = t & 255;
            v = W1[(size_t)k * 1024 + m];
        }
        else {
            int t = gid - 1441792; int m = t >> 10; int k = t & 1023;
            v = W2[(size_t)k * 256 + m];
        }
        Wt[gid] = f2bf(v);
    }
    if (gid < 5888) {
        float v;
        if (gid < 256) v = bu[gid];
        else if (gid < 4352) {
            int t = gid - 256; int d = t >> 10; int r = t & 1023;
            v = (r < 768) ? bw[d * 768 + r] : bl[d * 256 + (r - 768)];
        }
        else if (gid < 4608) v = bo[gid - 4352];
        else if (gid < 5632) v = b1[gid - 4608];
        else v = b2[gid - 5632];
        biasP[gid] = v;
    }
}

// fp32 channel-major [B][256][4096] -> bf16 pixel-major [B][4096][256]
__global__ __launch_bounds__(256) void transpose_to_bf(
    const float* __restrict__ src, unsigned short* __restrict__ dst)
{
    __shared__ float T[64][65];
    const int t = threadIdx.x;
    const int n0 = blockIdx.x * 64, c0 = blockIdx.y * 64, b = blockIdx.z;
    const int nl = t & 63, cg = t >> 6;
#pragma unroll
    for (int i = 0; i < 16; ++i) {
        int cl = cg + i * 4;
        T[cl][nl] = src[((size_t)b * 256 + c0 + cl) * HW + n0 + nl];
    }
    __syncthreads();
#pragma unroll
    for (int i = 0; i < 16; ++i) {
        int nl2 = cg + i * 4;
        dst[((size_t)b * HW + n0 + nl2) * 256 + c0 + (t & 63)] = f2bf(T[t & 63][nl2]);
    }
}

// MFMA GEMM, 128x128 tile, 4 waves 2x2, 16x16x32, BK=32.
// 2-buf counted pipeline (r13-validated). Mst = CM batch row-stride
// (decouples output buffer layout from logical M for the fused u+taps GEMM).
__global__ __launch_bounds__(256) void gemm_mfma(
    const unsigned short* __restrict__ Abf,
    const unsigned short* __restrict__ Wbf,
    const float* __restrict__ bias,
    int K, int M, int Mst,
    float* __restrict__ outCM,
    unsigned short* __restrict__ outCMh,
    unsigned short* __restrict__ outPM,
    const unsigned short* __restrict__ resPM,
    int epi)
{
    __shared__ __align__(16) char SMEM[32768];     // 2 bufs x (A 8KB + B 8KB)
    const int tid = threadIdx.x;
    const int w = tid >> 6, l = tid & 63;
    const int n0 = blockIdx.x * 128;
    const int m0 = blockIdx.y * 128;
    const int bz = blockIdx.z;
    const int wpi = w >> 1, wcj = w & 1;
    const int lr = l & 15, lg = l >> 4;

    const unsigned short* Ab = Abf + (size_t)bz * HW * K;

    f32x4 acc[4][4];
#pragma unroll
    for (int i = 0; i < 4; ++i)
#pragma unroll
        for (int j = 0; j < 4; ++j) acc[i][j] = (f32x4)0.f;

    const int sko = (((l & 3) ^ ((l >> 3) & 3)) * 8);   // swizzled k-chunk (elems)
    const int rsw = (lr >> 1) & 3;                      // read-side XOR
    const int row_l = (l >> 2);

    const int c0 = w * 2, c1 = c0 + 1;
    const unsigned short* pA0 = Ab  + (size_t)(n0 + c0 * 16 + row_l) * K + sko;
    const unsigned short* pA1 = Ab  + (size_t)(n0 + c1 * 16 + row_l) * K + sko;
    const unsigned short* pB0 = Wbf + (size_t)(m0 + c0 * 16 + row_l) * K + sko;
    const unsigned short* pB1 = Wbf + (size_t)(m0 + c1 * 16 + row_l) * K + sko;
    const int dA0 = c0 * 1024, dA1 = c1 * 1024;
    const int dB0 = 8192 + c0 * 1024, dB1 = 8192 + c1 * 1024;

#define STAGE(buf, kk)                                                         \
    {                                                                          \
        gload16(pA0 + (kk), SMEM + (buf) * 16384 + dA0);                       \
        gload16(pB0 + (kk), SMEM + (buf) * 16384 + dB0);                       \
        gload16(pA1 + (kk), SMEM + (buf) * 16384 + dA1);                       \
        gload16(pB1 + (kk), SMEM + (buf) * 16384 + dB1);                       \
    }

    const int NS = K >> 5;
    STAGE(0, 0);
    int cur = 0;
    for (int t = 0; t < NS; ++t) {
        if (t + 1 < NS) {
            STAGE(cur ^ 1, (t + 1) * 32);
            asm volatile("s_waitcnt vmcnt(4)" ::: "memory");
        } else {
            asm volatile("s_waitcnt vmcnt(0)" ::: "memory");
        }
        __builtin_amdgcn_s_barrier();
        const short* Ac = (const short*)(SMEM + cur * 16384);
        const short* Bc = (const short*)(SMEM + cur * 16384 + 8192);
        s16x8 av[4], bv[4];
#pragma unroll
        for (int f = 0; f < 4; ++f) {
            av[f] = *(const s16x8*)&Ac[(wpi * 64 + f * 16 + lr) * 32 + (lg ^ rsw) * 8];
            bv[f] = *(const s16x8*)&Bc[(wcj * 64 + f * 16 + lr) * 32 + (lg ^ rsw) * 8];
        }
        __builtin_amdgcn_s_setprio(1);
#pragma unroll
        for (int fi = 0; fi < 4; ++fi)
#pragma unroll
            for (int fj = 0; fj < 4; ++fj)
                acc[fi][fj] = mfma_bf16(av[fi], bv[fj], acc[fi][fj]);
        __builtin_amdgcn_s_setprio(0);
        __builtin_amdgcn_s_barrier();
        cur ^= 1;
    }
#undef STAGE

    unsigned short* RP = (unsigned short*)SMEM;    // 128x128 bf16 PM repack

#pragma unroll
    for (int fi = 0; fi < 4; ++fi) {
#pragma unroll
        for (int fj = 0; fj < 4; ++fj) {
            const int m = m0 + wcj * 64 + fj * 16 + lr;
            const int nl = wpi * 64 + fi * 16 + lg * 4;
            const float bs = bias[m];
            const size_t oc = ((size_t)bz * Mst + m) * HW + n0 + nl;
            float4 v4;
            float* vp = &v4.x;
#pragma unroll
            for (int r = 0; r < 4; ++r) vp[r] = acc[fi][fj][r] + bs;
            if (epi == E_GELU) {
                // x*sigmoid(1.702x): |err| <= 0.021 vs exact-erf GELU
#pragma unroll
                for (int r = 0; r < 4; ++r)
                    vp[r] = vp[r] / (1.f + __expf(-1.702f * vp[r]));
            } else if (epi == E_RESPM) {
#pragma unroll
                for (int r = 0; r < 4; ++r)
                    vp[r] += bf2f(resPM[((size_t)bz * HW + n0 + nl + r) * 256 + m]);
            }
            if (outCM)  *(float4*)&outCM[oc] = v4;
            if (outCMh) {
                uint2 p;
                p.x = cvt_pk_bf16(v4.x, v4.y);
                p.y = cvt_pk_bf16(v4.z, v4.w);
                *(uint2*)&outCMh[oc] = p;
            }
            if (outPM) {
                const int ml = wcj * 64 + fj * 16 + lr;
                const unsigned p01 = cvt_pk_bf16(vp[0], vp[1]);
                const unsigned p23 = cvt_pk_bf16(vp[2], vp[3]);
                RP[(nl + 0) * 128 + ml] = (unsigned short)p01;
                RP[(nl + 1) * 128 + ml] = (unsigned short)(p01 >> 16);
                RP[(nl + 2) * 128 + ml] = (unsigned short)p23;
                RP[(nl + 3) * 128 + ml] = (unsigned short)(p23 >> 16);
            }
        }
    }

    if (outPM) {
        __syncthreads();
#pragma unroll
        for (int i = 0; i < 8; ++i) {
            const int flat = i * 4096 + tid * 16;
            const int nl = flat >> 8;
            const int mlb = flat & 255;
            *(us16x8*)&outPM[((size_t)bz * HW + n0 + nl) * M + m0 + (mlb >> 1)] =
                *(const us16x8*)((const char*)RP + flat);
        }
    }
}

// Row-direction scans (dirs 0/1), register-prefetched. w3/lam/u live in the
// combined [B][1280][HW] bf16 buffer (batch stride MROWS*HW); y f32 stride 256*HW.
__global__ __launch_bounds__(256) void scan_dir(
    const unsigned short* __restrict__ w3,
    const unsigned short* __restrict__ lam,
    const unsigned short* __restrict__ u,
    float* __restrict__ y,
    int dir, int overwrite)
{
    const int wave = threadIdx.x >> 6;
    const int lane = threadIdx.x & 63;
    const int plane = blockIdx.x * 4 + wave;
    const int b = plane >> 8;
    const int c = plane & 255;

    const size_t base_w = (size_t)b * (MROWS * HW) + (size_t)c * HW;
    const size_t base_y = ((size_t)b * CDIM + c) * HW;
    const size_t tapstr = (size_t)CDIM * HW;

    int p = (dir == 1) ? 63 : 0;
    size_t off = (size_t)p * WD + lane;
    float w0 = bf2f(w3[base_w + off]);
    float w1 = bf2f(w3[base_w + tapstr + off]);
    float w2 = bf2f(w3[base_w + 2 * tapstr + off]);
    float lmr = bf2f(lam[base_w + off]);
    float uu = bf2f(u[base_w + off]);
    float yv = overwrite ? 0.f : y[base_y + off];

    float h = 0.f;
    for (int s = 0; s < 64; ++s) {
        float nw0 = 0.f, nw1 = 0.f, nw2 = 0.f, nlm = 0.f, nuu = 0.f, nyv = 0.f;
        size_t noff = 0;
        if (s + 1 < 64) {
            const int pn = (dir == 1) ? (62 - s) : (s + 1);
            noff = (size_t)pn * WD + lane;
            nw0 = bf2f(w3[base_w + noff]);
            nw1 = bf2f(w3[base_w + tapstr + noff]);
            nw2 = bf2f(w3[base_w + 2 * tapstr + noff]);
            nlm = bf2f(lam[base_w + noff]);
            nuu = bf2f(u[base_w + noff]);
            if (!overwrite) nyv = y[base_y + noff];
        }
        float dn = 1.0f / (fabsf(w0) + fabsf(w1) + fabsf(w2) + 1e-6f);
        float lm = 1.f / (1.f + __expf(-lmr));
        float hl = __shfl_up(h, 1);
        float hr = __shfl_down(h, 1);
        if (lane == 0)  hl = 0.f;
        if (lane == 63) hr = 0.f;
        h = (w0 * hl + w1 * h + w2 * hr) * dn + lm * uu;
        y[base_y + off] = yv + h;
        off = noff;
        w0 = nw0; w1 = nw1; w2 = nw2; lmr = nlm; uu = nuu; yv = nyv;
    }
}

// Column-direction scans (dirs 2/3): CHT=32 full-line chunks, column-major
// LDS, register-prefetch of chunk B. Strides per combined buffer.
__global__ __launch_bounds__(128) void scan_dir_t(
    const unsigned short* __restrict__ w3,
    const unsigned short* __restrict__ lam,
    const unsigned short* __restrict__ u,
    float* __restrict__ y,
    int dir)
{
    __shared__ unsigned short TH[2][4][CHT][66];   // 33.0 KB
    __shared__ float U[2][CHT][65];                // 16.25 KB
    const int wv = threadIdx.x >> 6;
    const int lane = threadIdx.x & 63;
    const int plane = blockIdx.x * 2 + wv;
    const int b = plane >> 8;
    const int c = plane & 255;

    const size_t base_w = (size_t)b * (MROWS * HW) + (size_t)c * HW;
    const size_t base_y = ((size_t)b * CDIM + c) * HW;
    const size_t tapstr = (size_t)CDIM * HW;
    const int rr4 = lane >> 2, q4 = lane & 3;
    const int rr8 = lane >> 3, q8 = lane & 7;

    const int p0A = (dir == 3) ? CHT : 0;
    const int p0B = CHT - p0A;

    // stage chunk A into LDS
#pragma unroll
    for (int a = 0; a < 4; ++a) {
        const unsigned short* s = (a < 3) ? (w3 + base_w + a * tapstr)
                                          : (lam + base_w);
#pragma unroll
        for (int i = 0; i < 4; ++i) {
            const int r = i * 16 + rr4;
            const us16x8 v = *(const us16x8*)(s + (size_t)r * WD + p0A + q4 * 8);
#pragma unroll
            for (int j = 0; j < 8; ++j) TH[wv][a][q4 * 8 + j][r] = v[j];
        }
    }
#pragma unroll
    for (int i = 0; i < 4; ++i) {
        const int r = i * 16 + rr4;
        const us16x8 v = *(const us16x8*)(u + base_w + (size_t)r * WD + p0A + q4 * 8);
#pragma unroll
        for (int j = 0; j < 8; ++j) U[wv][q4 * 8 + j][r] = bf2f(v[j]);
    }

    // prefetch chunk B into registers
    us16x8 pfT[4][4], pfU[4];
#pragma unroll
    for (int a = 0; a < 4; ++a) {
        const unsigned short* s = (a < 3) ? (w3 + base_w + a * tapstr)
                                          : (lam + base_w);
#pragma unroll
        for (int i = 0; i < 4; ++i)
            pfT[a][i] = *(const us16x8*)(s + (size_t)(i * 16 + rr4) * WD + p0B + q4 * 8);
    }
#pragma unroll
    for (int i = 0; i < 4; ++i)
        pfU[i] = *(const us16x8*)(u + base_w + (size_t)(i * 16 + rr4) * WD + p0B + q4 * 8);

    float h = 0.f;

    auto SCAN = [&]() {
        for (int t = 0; t < CHT; ++t) {
            const int pp = (dir == 3) ? (CHT - 1 - t) : t;
            float w0 = bf2f(TH[wv][0][pp][lane]);
            float w1 = bf2f(TH[wv][1][pp][lane]);
            float w2 = bf2f(TH[wv][2][pp][lane]);
            float dn = 1.0f / (fabsf(w0) + fabsf(w1) + fabsf(w2) + 1e-6f);
            float lm = 1.f / (1.f + __expf(-bf2f(TH[wv][3][pp][lane])));
            float uu = U[wv][pp][lane];

            float hl = __shfl_up(h, 1);
            float hr = __shfl_down(h, 1);
            if (lane == 0)  hl = 0.f;
            if (lane == 63) hr = 0.f;

            h = (w0 * hl + w1 * h + w2 * hr) * dn + lm * uu;
            U[wv][pp][lane] = h;
        }
    };
    auto YRMW = [&](int p0) {
#pragma unroll
        for (int i = 0; i < 8; ++i) {
            const int r = i * 8 + rr8;
            const size_t g = base_y + (size_t)r * WD + p0 + q8 * 4;
            float4 old = *(const float4*)(y + g);
            old.x += U[wv][q8 * 4 + 0][r];
            old.y += U[wv][q8 * 4 + 1][r];
            old.z += U[wv][q8 * 4 + 2][r];
            old.w += U[wv][q8 * 4 + 3][r];
            *(float4*)(y + g) = old;
        }
    };

    SCAN();
    YRMW(p0A);

    // commit prefetched chunk B (same-wave in-order)
#pragma unroll
    for (int a = 0; a < 4; ++a)
#pragma unroll
        for (int i = 0; i < 4; ++i) {
            const int r = i * 16 + rr4;
#pragma unroll
            for (int j = 0; j < 8; ++j) TH[wv][a][q4 * 8 + j][r] = pfT[a][i][j];
        }
#pragma unroll
    for (int i = 0; i < 4; ++i) {
        const int r = i * 16 + rr4;
#pragma unroll
        for (int j = 0; j < 8; ++j) U[wv][q4 * 8 + j][r] = bf2f(pfU[i][j]);
    }

    SCAN();
    YRMW(p0B);
}

extern "C" void kernel_launch(void* const* d_in, const int* in_sizes, int n_in,
                              void* d_out, int out_size, void* d_ws, size_t ws_size,
                              hipStream_t stream)
{
    const float* x  = (const float*)d_in[0];
    const float* Wu = (const float*)d_in[1];
    const float* bu = (const float*)d_in[2];
    const float* Ww = (const float*)d_in[3];
    const float* bw = (const float*)d_in[4];
    const float* Wl = (const float*)d_in[5];
    const float* bl = (const float*)d_in[6];
    const float* Wo = (const float*)d_in[7];
    const float* bo = (const float*)d_in[8];
    const float* W1 = (const float*)d_in[9];
    const float* b1 = (const float*)d_in[10];
    const float* W2 = (const float*)d_in[11];
    const float* b2 = (const float*)d_in[12];
    float* out = (float*)d_out;

    // ws layout (~172 MB; >=188 proven):
    // uwl: [8][1280][4096] bf16 -- rows 0-255 = u, 256-1023 taps, 1024-1279 lam(raw)
    unsigned short* uwl = (unsigned short*)d_ws;
    float* y_  = (float*)(uwl + (size_t)BATCH * MROWS * HW);   // [8][256][4096] f32
    unsigned short* xT  = (unsigned short*)(y_ + 8388608);     // [8][4096][256] bf16
    unsigned short* yT  = xT + 8388608;
    unsigned short* x2T = yT + 8388608;
    unsigned short* Wt  = x2T + 8388608;
    float* biasP = (float*)(Wt + 1703936);
    unsigned short* hT = uwl;                                  // [8][4096][1024] bf16 alias
    unsigned short* w3p  = uwl + (size_t)256 * HW;             // taps base (per-batch rows 256+)
    unsigned short* lamp = uwl + (size_t)1024 * HW;            // lam base

    dim3 blk(256);

    pack_weights<<<dim3(6656), blk, 0, stream>>>(Wu, Ww, Wl, Wo, W1, W2,
                                                 bu, bw, bl, bo, b1, b2, Wt, biasP);
    transpose_to_bf<<<dim3(64, 4, 8), blk, 0, stream>>>(x, xT);

    for (int dir = 0; dir < 4; ++dir) {
        if (dir == 0) {
            // fused u(256) + taps(768) + lam(256) GEMM, M=1280 rows contiguous in Wt
            gemm_mfma<<<dim3(32, 10, 8), blk, 0, stream>>>(
                xT, Wt, biasP, 256, 1280, MROWS,
                nullptr, uwl, nullptr, nullptr, E_NONE);
        } else {
            // taps+lam for this dir -> rows 256.. of uwl (Mst=1280)
            gemm_mfma<<<dim3(32, 8, 8), blk, 0, stream>>>(
                xT, Wt + 65536 + (size_t)dir * 262144, biasP + 256 + dir * 1024,
                256, 1024, MROWS, nullptr, w3p, nullptr, nullptr, E_NONE);
        }
        if (dir < 2)
            scan_dir<<<dim3(512), blk, 0, stream>>>(w3p, lamp, uwl, y_,
                                                    dir, dir == 0 ? 1 : 0);
        else
            scan_dir_t<<<dim3(1024), dim3(128), 0, stream>>>(w3p, lamp, uwl, y_, dir);
    }

    transpose_to_bf<<<dim3(64, 4, 8), blk, 0, stream>>>(y_, yT);

    // x2 = x + Wo @ y + bo : bf16 PM only; residual from xT (bf16 PM)
    gemm_mfma<<<dim3(32, 2, 8), blk, 0, stream>>>(yT, Wt + 1114112, biasP + 4352,
        256, 256, 256, nullptr, nullptr, x2T, xT, E_RESPM);
    // h = gelu(x2 @ W1 + b1) : bf16 PM only
    gemm_mfma<<<dim3(32, 8, 8), blk, 0, stream>>>(x2T, Wt + 1179648, biasP + 4608,
        256, 1024, 1024, nullptr, nullptr, hT, nullptr, E_GELU);
    // out = x2 + h @ W2 + b2 : f32 CM = d_out, residual from x2T (PM bf16)
    gemm_mfma<<<dim3(32, 2, 8), blk, 0, stream>>>(hT, Wt + 1441792, biasP + 5632,
        1024, 256, 256, out, nullptr, nullptr, x2T, E_RESPM);
}